// Round 9
// baseline (1244.271 us; speedup 1.0000x reference)
//
#include <hip/hip_runtime.h>
#include <math.h>

#define N_NODES 100000
#define N_EDGES 3200000
#define SCAN_NB ((N_NODES + 255) / 256)   // 391
#define X_FLOATS (N_NODES * 131)          // 13,100,000

// Sharded scatter: 8 dst-shards (one per XCD via blockIdx%8 round-robin heuristic)
#define N_SHARDS 8
#define NODES_PER_SHARD (N_NODES / N_SHARDS)   // 12500
#define N_CHUNKS 800
#define EDGES_PER_CHUNK (N_EDGES / N_CHUNKS)   // 4000

// MLP pass A tiling: 128-node tile, k staged in 4 chunks of <=33
#define TILE_NODES 128
#define KCH 33
#define MLP1_NB ((N_NODES + TILE_NODES - 1) / TILE_NODES)   // 782

// ---------------- CSR build ----------------

__global__ void k_init(int* __restrict__ count) {
    int i = blockIdx.x * blockDim.x + threadIdx.x;
    if (i < N_NODES) count[i] = 0;
}

__global__ void k_hist(const int* __restrict__ dst, int* __restrict__ count) {
    int e = blockIdx.x * blockDim.x + threadIdx.x;   // grid sized exactly E
    int d = __builtin_nontemporal_load(&dst[e]);
    atomicAdd(&count[d], 1);
}

__global__ __launch_bounds__(256) void k_scan1(const int* __restrict__ count,
                                               int* __restrict__ row_start,
                                               int* __restrict__ bsum) {
    __shared__ int tmp[256];
    const int t = threadIdx.x;
    const int i = blockIdx.x * 256 + t;
    int v = (i < N_NODES) ? count[i] : 0;
    tmp[t] = v;
    __syncthreads();
    for (int off = 1; off < 256; off <<= 1) {
        int a = (t >= off) ? tmp[t - off] : 0;
        __syncthreads();
        tmp[t] += a;
        __syncthreads();
    }
    if (i < N_NODES) row_start[i] = tmp[t] - v;   // exclusive
    if (t == 255) bsum[blockIdx.x] = tmp[255];
}

__global__ __launch_bounds__(512) void k_scan2(int* __restrict__ bsum) {
    __shared__ int tmp[512];
    const int t = threadIdx.x;
    int v = (t < SCAN_NB) ? bsum[t] : 0;
    tmp[t] = v;
    __syncthreads();
    for (int off = 1; off < 512; off <<= 1) {
        int a = (t >= off) ? tmp[t - off] : 0;
        __syncthreads();
        tmp[t] += a;
        __syncthreads();
    }
    if (t < SCAN_NB) bsum[t] = tmp[t] - v;   // exclusive
}

__global__ __launch_bounds__(256) void k_scan3(const int* __restrict__ count,
                                               int* __restrict__ row_start,
                                               const int* __restrict__ bsum,
                                               int* __restrict__ cursor,
                                               float* __restrict__ dinv) {
    const int i = blockIdx.x * 256 + threadIdx.x;
    if (i >= N_NODES) return;
    int rs = row_start[i] + bsum[blockIdx.x];
    row_start[i] = rs;
    cursor[i] = rs;
    dinv[i] = 1.0f / sqrtf((float)(count[i] + 1));   // deg includes self-loop
}

__global__ __launch_bounds__(256) void k_scatter(const int* __restrict__ src,
                                                 const int* __restrict__ dst,
                                                 int* __restrict__ cursor,
                                                 int* __restrict__ csr_src) {
    const int shard = blockIdx.x & (N_SHARDS - 1);
    const int chunk = blockIdx.x >> 3;
    const int lo = shard * NODES_PER_SHARD;
    const int hi = lo + NODES_PER_SHARD;
    const int e0 = chunk * EDGES_PER_CHUNK;
    const int e1 = e0 + EDGES_PER_CHUNK;
    for (int e = e0 + threadIdx.x; e < e1; e += 256) {
        int d = __builtin_nontemporal_load(&dst[e]);
        if (d >= lo && d < hi) {
            int s = __builtin_nontemporal_load(&src[e]);
            int pos = atomicAdd(&cursor[d], 1);
            csr_src[pos] = s;
        }
    }
}

// ---------------- MLP pass A: layer 1 (131 -> 64), k-chunked LDS staging ----------------

__global__ __launch_bounds__(256) void k_mlp1(
        const float* __restrict__ x,
        const float* __restrict__ W1, const float* __restrict__ b1,
        float* __restrict__ h1T) {
    __shared__ float xs[TILE_NODES * KCH];   // 16896 B
    const int t = threadIdx.x;
    const int nl = t & 127;
    const int half_u = __builtin_amdgcn_readfirstlane(t >> 7);  // wave-uniform
    const int nbase = blockIdx.x * TILE_NODES;
    const int node = nbase + nl;

    float a[32];
#pragma unroll
    for (int j = 0; j < 32; ++j) a[j] = b1[half_u * 32 + j];

    for (int kc = 0; kc < 4; ++kc) {
        const int k0 = kc * KCH;
        const int len = (k0 + KCH <= 131) ? KCH : (131 - k0);   // 33,33,33,32
        __syncthreads();
        for (int i = t; i < TILE_NODES * KCH; i += 256) {
            int r = i / KCH;
            int c = i - r * KCH;
            int gr = nbase + r;
            xs[i] = (c < len && gr < N_NODES) ? x[(long)gr * 131 + k0 + c] : 0.0f;
        }
        __syncthreads();
        const float* myrow = xs + nl * KCH;
        for (int kk = 0; kk < len; ++kk) {
            float xk = myrow[kk];
            const float* wr = W1 + (k0 + kk) * 64 + half_u * 32;   // uniform -> s_load
#pragma unroll
            for (int j = 0; j < 32; ++j) a[j] += xk * wr[j];
        }
    }

    if (node < N_NODES) {
#pragma unroll
        for (int j = 0; j < 32; ++j)
            h1T[(half_u * 32 + j) * N_NODES + node] = tanhf(a[j]);
    }
}

// ---------------- MLP pass B: 64 -> 32 -> 16 -> conv-fuse ----------------
// Writes u0 row-major: u[node*16 + j] = (h3 @ Wc1)[j] * dinv[node]

__global__ __launch_bounds__(256) void k_mlp2(
        const float* __restrict__ h1T,
        const float* __restrict__ W2, const float* __restrict__ b2,
        const float* __restrict__ W3, const float* __restrict__ b3,
        const float* __restrict__ Wc1,
        const float* __restrict__ dinv,
        float* __restrict__ u0) {
    const int node = blockIdx.x * 256 + threadIdx.x;
    if (node >= N_NODES) return;

    float a2[32];
#pragma unroll
    for (int j = 0; j < 32; ++j) a2[j] = b2[j];
    for (int k = 0; k < 64; ++k) {
        float hk = h1T[k * N_NODES + node];           // coalesced
        const float* wr = W2 + k * 32;                // uniform -> s_load
#pragma unroll
        for (int j = 0; j < 32; ++j) a2[j] += hk * wr[j];
    }
#pragma unroll
    for (int j = 0; j < 32; ++j) a2[j] = tanhf(a2[j]);

    float a3[16];
#pragma unroll
    for (int j = 0; j < 16; ++j) a3[j] = b3[j];
#pragma unroll 4
    for (int k = 0; k < 32; ++k) {
        float hk = a2[k];
        const float* wr = W3 + k * 16;
#pragma unroll
        for (int j = 0; j < 16; ++j) a3[j] += hk * wr[j];
    }

    float dv = dinv[node];
    float uo[16];
#pragma unroll
    for (int j = 0; j < 16; ++j) uo[j] = 0.0f;
#pragma unroll 4
    for (int k = 0; k < 16; ++k) {
        float hk = a3[k];
        const float* wr = Wc1 + k * 16;
#pragma unroll
        for (int j = 0; j < 16; ++j) uo[j] += hk * wr[j];
    }
    float4* ur = reinterpret_cast<float4*>(u0 + (long)node * 16);
#pragma unroll
    for (int q = 0; q < 4; ++q) {
        float4 v;
        v.x = uo[4 * q + 0] * dv;
        v.y = uo[4 * q + 1] * dv;
        v.z = uo[4 * q + 2] * dv;
        v.w = uo[4 * q + 3] * dv;
        ur[q] = v;
    }
}

// ---------------- Fused conv layer: aggregate + tanh + next-layer transform ----------------
// One wave per node: lane = (grp 0..3, feat 0..15). Full 64B row gathers (every
// fetched line fully consumed), csr read once. Transform via 4-way k-split with
// LDS-staged W (stride-17 pad -> conflict-free; staged with a STRIDED loop — the
// R8 bug was `if (t < 272)` with only 256 threads, leaving sW[256..271] garbage).
// mode 0: u_next[i] = (tanh(dv*(sum+self)+b) @ Wn) * dv
// mode 1: out[0..2N) = h @ Wcls + bcls; out[2N..) = h rows

__global__ __launch_bounds__(256) void k_layer(
        const float* __restrict__ u,
        const int* __restrict__ row_start,
        const int* __restrict__ count,
        const int* __restrict__ csr_src,
        const float* __restrict__ dinv,
        const float* __restrict__ bias,
        const float* __restrict__ Wn,
        const float* __restrict__ Wcls,
        const float* __restrict__ bcls,
        float* __restrict__ u_next,
        float* __restrict__ out,
        int mode) {
    __shared__ float sW[272];   // 16 rows, stride 17 (pad breaks 4-way bank conflict)
    __shared__ float sWc[32];
    __shared__ float sb[16];
    __shared__ float sc[2];
    const int t = threadIdx.x;
    if (mode == 0) {
        for (int i = t; i < 272; i += 256) {          // strided: covers all 272 slots
            int k = i / 17, c = i - k * 17;
            sW[i] = (c < 16) ? Wn[k * 16 + c] : 0.0f;
        }
    } else {
        if (t < 32) sWc[t] = Wcls[t];
        if (t < 2) sc[t] = bcls[t];
    }
    if (t < 16) sb[t] = bias[t];
    __syncthreads();

    const int wave = t >> 6;
    const int lane = t & 63;
    const int f = lane & 15;
    const int grp = lane >> 4;
    const int gbase = lane & 48;              // start lane of my 16-lane group
    const int node = blockIdx.x * 4 + wave;   // grid*4 == N exactly

    const int rs = __builtin_amdgcn_readfirstlane(row_start[node]);
    const int cnt = __builtin_amdgcn_readfirstlane(count[node]);
    const float dv = dinv[node];

    float acc = 0.0f;
    for (int base = 0; base < cnt; base += 64) {
        // one coalesced load covers 64 edge indices (overread past row end is
        // masked below; overread past csr array lands in u buffers: safe)
        int idx = csr_src[rs + base + lane];
#pragma unroll
        for (int k = 0; k < 16; ++k) {
            int e = base + 4 * k + grp;
            int s = __shfl(idx, 4 * k + grp, 64);
            if (e < cnt) acc += u[(long)s * 16 + f];
        }
    }
    acc += __shfl_xor(acc, 16, 64);
    acc += __shfl_xor(acc, 32, 64);
    acc += u[(long)node * 16 + f];            // self-loop (u pre-scaled by dinv[src])

    float hn = tanhf(dv * acc + sb[f]);       // replicated across the 4 groups

    if (mode == 0) {
        float tt = 0.0f;
#pragma unroll
        for (int j = 0; j < 4; ++j) {
            int k = 4 * grp + j;
            float hk = __shfl(hn, gbase + k, 64);   // group-local: hn replicated
            tt += hk * sW[k * 17 + f];
        }
        tt += __shfl_xor(tt, 16, 64);
        tt += __shfl_xor(tt, 32, 64);
        if (grp == 0) u_next[(long)node * 16 + f] = tt * dv;
    } else {
        float tc = 0.0f;
#pragma unroll
        for (int j = 0; j < 4; ++j) {
            int k = 4 * grp + j;
            float hk = __shfl(hn, gbase + k, 64);
            tc += hk * sWc[k * 2 + (f & 1)];
        }
        tc += __shfl_xor(tc, 16, 64);
        tc += __shfl_xor(tc, 32, 64);
        if (grp == 0) out[200000 + (long)node * 16 + f] = hn;
        if (grp == 1 && f < 2) out[(long)node * 2 + f] = tc + sc[f];
    }
}

// ---------------- launch ----------------

extern "C" void kernel_launch(void* const* d_in, const int* in_sizes, int n_in,
                              void* d_out, int out_size, void* d_ws, size_t ws_size,
                              hipStream_t stream) {
    const float* x    = (const float*)d_in[0];
    const int*   ei   = (const int*)d_in[1];
    const float* W1   = (const float*)d_in[2];
    const float* b1   = (const float*)d_in[3];
    const float* W2   = (const float*)d_in[4];
    const float* b2   = (const float*)d_in[5];
    const float* W3   = (const float*)d_in[6];
    const float* b3   = (const float*)d_in[7];
    const float* Wc1  = (const float*)d_in[8];
    const float* bc1  = (const float*)d_in[9];
    const float* Wg   = (const float*)d_in[10];
    const float* bg   = (const float*)d_in[11];
    const float* Wcls = (const float*)d_in[12];
    const float* bcls = (const float*)d_in[13];
    float* out = (float*)d_out;

    const int* src = ei;
    const int* dst = ei + N_EDGES;

    int* count     = (int*)d_ws;
    int* cursor    = count + N_NODES;
    int* row_start = cursor + N_NODES;
    float* dinv    = (float*)(row_start + N_NODES);
    int* csr_src   = (int*)(dinv + N_NODES);
    float* u_a     = (float*)(csr_src + N_EDGES);   // N*16 floats
    float* u_b     = u_a + (long)N_NODES * 16;      // N*16 floats
    float* h1T     = u_b + (long)N_NODES * 16;      // 64*N floats
    int* bsum      = csr_src;   // consumed by k_scan3 before k_scatter writes

    k_init<<<(N_NODES + 255) / 256, 256, 0, stream>>>(count);
    k_hist<<<N_EDGES / 256, 256, 0, stream>>>(dst, count);
    k_scan1<<<SCAN_NB, 256, 0, stream>>>(count, row_start, bsum);
    k_scan2<<<1, 512, 0, stream>>>(bsum);
    k_scan3<<<SCAN_NB, 256, 0, stream>>>(count, row_start, bsum, cursor, dinv);
    k_scatter<<<N_CHUNKS * N_SHARDS, 256, 0, stream>>>(src, dst, cursor, csr_src);
    k_mlp1<<<MLP1_NB, 256, 0, stream>>>(x, W1, b1, h1T);
    k_mlp2<<<SCAN_NB, 256, 0, stream>>>(h1T, W2, b2, W3, b3, Wc1, dinv, u_a);

    float* ua = u_a;
    float* ub = u_b;
    for (int j = 0; j < 10; ++j) {
        const float* bias = (j < 5) ? bc1 : (bg + (long)(j - 5) * 16);
        const float* Wn = (j < 4) ? Wc1 : (Wg + (long)(j - 4) * 256);  // j==9 unused
        int mode = (j == 9) ? 1 : 0;
        k_layer<<<N_NODES / 4, 256, 0, stream>>>(ua, row_start, count, csr_src, dinv,
                                                 bias, Wn, Wcls, bcls, ub, out, mode);
        float* tmp = ua; ua = ub; ub = tmp;
    }
}